// Round 5
// baseline (293.212 us; speedup 1.0000x reference)
//
#include <hip/hip_runtime.h>
#include <hip/hip_bf16.h>

typedef short bf16x8 __attribute__((ext_vector_type(8)));
typedef float f32x4  __attribute__((ext_vector_type(4)));
typedef float f32x2  __attribute__((ext_vector_type(2)));
typedef unsigned short us8 __attribute__((ext_vector_type(8)));

#define NT 512
// LDS layout (bytes): px granule = 80B (4 slots x 16B + 16B pad -> bank spread)
#define YROW 1936      // 24 granules * 80 + 16 pad  (row pad shifts bank phase)
#define XBASE 30976    // Y slab: 16 rows
#define XROW 1296      // 16 granules * 80 + 16 pad
#define EPBASE 41344   // X tile: 8 rows; then 8 waves x 768B epilogue
#define SMEM_SZ 47488

__device__ __forceinline__ unsigned short f2bf(float f) {
    __hip_bfloat16 h = __float2bfloat16(f);
    return reinterpret_cast<const unsigned short&>(h);
}

__global__ __launch_bounds__(NT, 4)
void corr_k(const float* __restrict__ x, const float* __restrict__ y,
            float* __restrict__ out)
{
    constexpr int H = 192, W = 192;
    constexpr int plane = H * W;
    constexpr unsigned PL4 = plane * 4u;

    __shared__ __align__(16) char smem[SMEM_SZ];

    // grid 1152 = 4b x 12wt x 24ht, XCD-chunked bijection, ht fastest (L2 locality)
    const int bid  = blockIdx.x;
    const int task = (bid & 7) * 144 + (bid >> 3);
    const int ht   = task % 24;
    const int r1   = task / 24;
    const int wt   = r1 % 12;
    const int b    = r1 / 12;
    const int h0 = ht * 8, w0 = wt * 16;

    const int tid  = threadIdx.x;
    const int wid  = tid >> 6, lane = tid & 63;
    const int lm = lane & 15, lg = lane >> 4;
    const int rp = wid >> 1;          // row pair: rows 2rp, 2rp+1
    const int half = wid & 1;         // dy half: 0 -> dy 0..3, 1 -> dy 4..8
    const int dy0  = half ? 4 : 0;

    const unsigned boff = (unsigned)b * 128u * PL4;

    // ---- staging descriptors: tid<384 stage y slab (16r x 24px), else x (8r x 16px)
    const char* gbase; unsigned goff0, goff1; float ok0, ok1; int lbase;
    if (tid < 384) {
        const int cg = tid & 3, pq = tid >> 2;       // cg: 8-ch group, pq: px quad
        const int row = pq / 6, pqi = pq % 6;
        const int hg = h0 - 4 + row;
        const int hc = min(max(hg, 0), H - 1);
        const int wg0 = w0 - 4 + pqi * 4;            // even; pairs never straddle edge
        const int wg1 = wg0 + 2;
        const int wc0 = min(max(wg0, 0), W - 2);
        const int wc1 = min(max(wg1, 0), W - 2);
        const bool okr = (hg >= 0) & (hg < H);
        ok0 = (okr & (wg0 >= 0) & (wg0 < W - 1)) ? 1.f : 0.f;
        ok1 = (okr & (wg1 >= 0) & (wg1 < W - 1)) ? 1.f : 0.f;
        gbase = (const char*)y;
        goff0 = boff + (unsigned)(cg * 8) * PL4 + (unsigned)(hc * W + wc0) * 4u;
        goff1 = boff + (unsigned)(cg * 8) * PL4 + (unsigned)(hc * W + wc1) * 4u;
        lbase = row * YROW + pqi * 4 * 80 + cg * 16;
    } else {
        const int t = tid - 384;
        const int cg = t & 3, pq = t >> 2;
        const int row = pq >> 2, pqi = pq & 3;
        ok0 = ok1 = 1.f;
        gbase = (const char*)x;
        const unsigned base = boff + (unsigned)(cg * 8) * PL4
                            + (unsigned)((h0 + row) * W + w0 + pqi * 4) * 4u;
        goff0 = base; goff1 = base + 8u;
        lbase = XBASE + row * XROW + pqi * 4 * 80 + cg * 16;
    }

    f32x2 pf[8];
    f32x4 acc[2][5][2];
#pragma unroll
    for (int r = 0; r < 2; ++r)
#pragma unroll
        for (int i = 0; i < 5; ++i) {
            acc[r][i][0] = (f32x4){0.f, 0.f, 0.f, 0.f};
            acc[r][i][1] = (f32x4){0.f, 0.f, 0.f, 0.f};
        }

    auto ISSUE = [&](unsigned off) {     // 8 coalesced float2 loads (8 ch-planes, 2 px)
#pragma unroll
        for (int j = 0; j < 8; ++j)
            pf[j] = *reinterpret_cast<const f32x2*>(gbase + off + (unsigned)j * PL4);
    };
    auto CVTW = [&](int bb, float ok) {  // regs -> bf16 -> 2x ds_write_b128
#pragma unroll
        for (int p = 0; p < 2; ++p) {
            us8 v = { f2bf(pf[0][p] * ok), f2bf(pf[1][p] * ok),
                      f2bf(pf[2][p] * ok), f2bf(pf[3][p] * ok),
                      f2bf(pf[4][p] * ok), f2bf(pf[5][p] * ok),
                      f2bf(pf[6][p] * ok), f2bf(pf[7][p] * ok) };
            *reinterpret_cast<us8*>(smem + lbase + (2 * bb + p) * 80) = v;
        }
    };
    auto COMPUTE = [&]() {
        const int rb = lm * 80 + lg * 16;
        const bf16x8 A0 = *reinterpret_cast<const bf16x8*>(
            smem + XBASE + (2 * rp) * XROW + rb);
        const bf16x8 A1 = *reinterpret_cast<const bf16x8*>(
            smem + XBASE + (2 * rp + 1) * XROW + rb);
#pragma unroll
        for (int i = 0; i < 5; ++i) {
            if (i < 4 || half) {                      // wave-uniform
                const char* y0 = smem + (2 * rp + dy0 + i) * YROW + rb;
                // nt=1, lm>=8 reads garbage (px>=24 wraps); band-masked in epilogue
                const bf16x8 b00 = *reinterpret_cast<const bf16x8*>(y0);
                const bf16x8 b01 = *reinterpret_cast<const bf16x8*>(y0 + 16 * 80);
                const bf16x8 b10 = *reinterpret_cast<const bf16x8*>(y0 + YROW);
                const bf16x8 b11 = *reinterpret_cast<const bf16x8*>(y0 + YROW + 16 * 80);
                acc[0][i][0] = __builtin_amdgcn_mfma_f32_16x16x32_bf16(A0, b00, acc[0][i][0], 0, 0, 0);
                acc[0][i][1] = __builtin_amdgcn_mfma_f32_16x16x32_bf16(A0, b01, acc[0][i][1], 0, 0, 0);
                acc[1][i][0] = __builtin_amdgcn_mfma_f32_16x16x32_bf16(A1, b10, acc[1][i][0], 0, 0, 0);
                acc[1][i][1] = __builtin_amdgcn_mfma_f32_16x16x32_bf16(A1, b11, acc[1][i][1], 0, 0, 0);
            }
        }
    };

    // ---- 4 chunks of K=32, single LDS buffer, batch-interleaved prefetch ----
    ISSUE(goff0);
#pragma unroll
    for (int c = 0; c < 4; ++c) {
        const unsigned co = (unsigned)c * 32u * PL4;
        CVTW(0, ok0);                    // auto vmcnt wait on pf
        ISSUE(goff1 + co);               // batch 1 of this chunk
        CVTW(1, ok1);
        if (c < 3) ISSUE(goff0 + co + 32u * PL4);  // next chunk; hides under bar+MFMA
        __syncthreads();                 // slab ready
        COMPUTE();
        __syncthreads();                 // all reads done before next overwrite
    }

    // ---- epilogue: band-extract P[m, m+dx], stride-17 per-wave LDS transpose ----
    const float invc = 1.0f / 128.0f;
    float* my = (float*)(smem + EPBASE) + wid * 192;
    int woff[8];
#pragma unroll
    for (int q = 0; q < 8; ++q) {
        const int nt = q >> 2, j = q & 3;
        const int m = lg * 4 + j;                 // D row = m (x pixel)
        const int dxx = lm + nt * 16 - m;         // D col - m = dx
        woff[q] = (dxx >= 0 && dxx <= 8) ? dxx * 17 + m : 160 + (lane & 31);
    }
    int ridx[3], soff[3];
#pragma unroll
    for (int p = 0; p < 3; ++p) {
        const int idx = p * 64 + lane;            // valid < 144
        const int dxr = idx >> 4, mr = idx & 15;
        ridx[p] = dxr * 17 + mr;
        soff[p] = dxr * plane + mr;
    }
#pragma unroll
    for (int rr = 0; rr < 2; ++rr) {
        float* ob = out + (size_t)b * 81 * plane + (size_t)(h0 + 2 * rp + rr) * W + w0;
#pragma unroll
        for (int i = 0; i < 5; ++i) {
            if (i < 4 || half) {
                const int dy = dy0 + i;
#pragma unroll
                for (int q = 0; q < 8; ++q)
                    my[woff[q]] = acc[rr][i][q >> 2][q & 3] * invc;
                const int dyo = dy * 9 * plane;
#pragma unroll
                for (int p = 0; p < 3; ++p)
                    if (p < 2 || lane < 16)
                        __builtin_nontemporal_store(my[ridx[p]], &ob[dyo + soff[p]]);
            }
        }
    }
}

extern "C" void kernel_launch(void* const* d_in, const int* in_sizes, int n_in,
                              void* d_out, int out_size, void* d_ws, size_t ws_size,
                              hipStream_t stream)
{
    const float* x = (const float*)d_in[0];
    const float* y = (const float*)d_in[1];
    float* out = (float*)d_out;
    // kernel_size=9, stride=1 fixed by setup_inputs; hardcoded above.
    corr_k<<<1152, NT, 0, stream>>>(x, y, out);
}

// Round 6
// 246.533 us; speedup vs baseline: 1.1893x; 1.1893x over previous
//
#include <hip/hip_runtime.h>
#include <hip/hip_bf16.h>

typedef short bf16x8 __attribute__((ext_vector_type(8)));
typedef float f32x4  __attribute__((ext_vector_type(4)));
typedef unsigned short us8 __attribute__((ext_vector_type(8)));

#define NT 512
// LDS byte layout (single block = 74752 B -> 2 blocks/CU on 160KB LDS)
#define YROW 1600    // 24 px * 64B + 64 pad (pad rotates bank phase per row)
#define YBUF 25600   // 16 slab rows
#define XROW 1088    // 16 px * 64B + 64 pad
#define XBASE 51200  // after 2 y buffers
#define XBUF 8704    // 8 rows
#define EPB  68608   // epilogue: 8 waves x 192 f32
#define SMEM_SZ 74752

__device__ __forceinline__ unsigned short f2bf(float f) {
    __hip_bfloat16 h = __float2bfloat16(f);
    return reinterpret_cast<const unsigned short&>(h);
}

__global__ __launch_bounds__(NT, 4)
void corr_k(const float* __restrict__ x, const float* __restrict__ y,
            float* __restrict__ out)
{
    constexpr int H = 192, W = 192;
    constexpr int plane = H * W;
    constexpr unsigned PL4 = plane * 4u;    // channel-plane byte stride
    constexpr unsigned CHB = 32u * PL4;     // K-chunk byte stride

    __shared__ __align__(16) char smem[SMEM_SZ];

    // grid 1152 = 8 xcd x 144; within XCD: wt fastest (round-2 ordering: FETCH 82MB)
    const int bid  = blockIdx.x;
    const int task = (bid & 7) * 144 + (bid >> 3);
    const int wt   = task % 12;
    const int r1   = task / 12;
    const int ht   = r1 % 24;
    const int b    = r1 / 24;
    const int h0 = ht * 8, w0 = wt * 16;

    const int tid  = threadIdx.x;
    const int wid  = tid >> 6, lane = tid & 63;   // wave = output row h0+wid
    const int lm = lane & 15, lg = lane >> 4;

    const unsigned boff = (unsigned)b * 128u * PL4;

    // ---- staging descriptors: tid<384 stage y slab (16r x 6 quads x 4 cg),
    //      tid>=384 stage x tile (8r x 4 quads x 4 cg); cg = 8-channel group ----
    const char* gb; unsigned goff; float okf; int lbase, bstride, cg;
    if (tid < 384) {
        cg = tid & 3;
        const int w4 = (tid >> 2) % 6, row = tid / 24;
        const int hg = h0 - 4 + row, wg = w0 - 4 + w4 * 4;   // quad never straddles
        okf = ((hg >= 0) & (hg < H) & (wg >= 0) & (wg <= W - 4)) ? 1.f : 0.f;
        const int hc = min(max(hg, 0), H - 1);
        const int wc = min(max(wg, 0), W - 4);
        gb   = (const char*)y;
        goff = boff + (unsigned)(cg * 8) * PL4 + (unsigned)(hc * W + wc) * 4u;
        lbase = row * YROW + w4 * 256;
        bstride = YBUF;
    } else {
        const int t = tid - 384;
        cg = t & 3;
        const int w4 = (t >> 2) & 3, row = t >> 4;
        okf = 1.f;
        gb   = (const char*)x;
        goff = boff + (unsigned)(cg * 8) * PL4
             + (unsigned)((h0 + row) * W + w0 + w4 * 4) * 4u;
        lbase = XBASE + row * XROW + w4 * 256;
        bstride = XBUF;
    }

    f32x4 pf[8];
    f32x4 acc[9][2];
#pragma unroll
    for (int i = 0; i < 9; ++i) {
        acc[i][0] = (f32x4){0.f, 0.f, 0.f, 0.f};
        acc[i][1] = (f32x4){0.f, 0.f, 0.f, 0.f};
    }

    auto ISSUE = [&](int c) {            // 8 x float4 (4 px from 8 ch-planes)
        const char* p = gb + goff + (unsigned)c * CHB;
#pragma unroll
        for (int j = 0; j < 8; ++j)
            pf[j] = *reinterpret_cast<const f32x4*>(p + (unsigned)j * PL4);
    };
    auto CVTW = [&](int c) {             // regs -> bf16 -> 4 x ds_write_b128
        char* d = smem + lbase + (c & 1) * bstride;
#pragma unroll
        for (int w = 0; w < 4; ++w) {
            us8 v = { f2bf(pf[0][w] * okf), f2bf(pf[1][w] * okf),
                      f2bf(pf[2][w] * okf), f2bf(pf[3][w] * okf),
                      f2bf(pf[4][w] * okf), f2bf(pf[5][w] * okf),
                      f2bf(pf[6][w] * okf), f2bf(pf[7][w] * okf) };
            *reinterpret_cast<us8*>(d + w * 64 + ((cg ^ w) << 4)) = v;   // slot=cg^w
        }
    };
    auto COMPUTE = [&](int c) {
        const int bs = c & 1;
        const int ro  = lm * 64 + ((lg ^ (lm & 3)) << 4);         // px=lm
        const int ro1 = ro + 1024;                                 // px=lm+16 (same sel)
        const bf16x8 A = *reinterpret_cast<const bf16x8*>(
            smem + XBASE + bs * XBUF + wid * XROW + ro);
        const char* yb = smem + bs * YBUF + wid * YROW;
#pragma unroll
        for (int i = 0; i < 9; ++i) {                              // dy = i
            const bf16x8 b0 = *reinterpret_cast<const bf16x8*>(yb + i * YROW + ro);
            const bf16x8 b1 = *reinterpret_cast<const bf16x8*>(yb + i * YROW + ro1);
            acc[i][0] = __builtin_amdgcn_mfma_f32_16x16x32_bf16(A, b0, acc[i][0], 0, 0, 0);
            acc[i][1] = __builtin_amdgcn_mfma_f32_16x16x32_bf16(A, b1, acc[i][1], 0, 0, 0);
        }
    };

    // ---- 4 K-chunks, double-buffered, ONE barrier per chunk, loads always in flight
    ISSUE(0);
    CVTW(0);
    ISSUE(1);
    __syncthreads();          // buf0 ready
    COMPUTE(0);
    CVTW(1);                  // waits on ISSUE(1); all waves past COMPUTE-0 reads? no:
    ISSUE(2);                 //   CVTW(1) writes buf1 (not buf0) -> safe pre-barrier
    __syncthreads();          // buf1 ready; everyone done reading buf0
    COMPUTE(1);
    CVTW(2);                  // overwrites buf0: all waves passed barrier after their
    ISSUE(3);                 //   COMPUTE(0) -> safe
    __syncthreads();
    COMPUTE(2);
    CVTW(3);
    __syncthreads();
    COMPUTE(3);

    // ---- epilogue: band-extract P[m, m+dx] via per-wave stride-17 LDS transpose ----
    const float invc = 1.0f / 128.0f;
    float* my = (float*)(smem + EPB) + wid * 192;
    int woff[8];
#pragma unroll
    for (int q = 0; q < 8; ++q) {
        const int nt = q >> 2, j = q & 3;
        const int m = lg * 4 + j;               // D row = m (x pixel)
        const int dxx = lm + nt * 16 - m;       // D col - m = dx
        woff[q] = (dxx >= 0 && dxx <= 8) ? dxx * 17 + m : 160 + (lane & 31);
    }
    int ridx[3], soff[3];
#pragma unroll
    for (int p = 0; p < 3; ++p) {
        const int idx = p * 64 + lane;          // valid < 144
        const int dxr = idx >> 4, mr = idx & 15;
        ridx[p] = dxr * 17 + mr;
        soff[p] = dxr * plane + mr;
    }
    float* ob = out + (size_t)b * 81 * plane + (size_t)(h0 + wid) * W + w0;
#pragma unroll
    for (int dy = 0; dy < 9; ++dy) {
#pragma unroll
        for (int q = 0; q < 8; ++q)
            my[woff[q]] = acc[dy][q >> 2][q & 3] * invc;
        const int dyo = dy * 9 * plane;
        // wave-local LDS write->read; compiler inserts lgkmcnt
#pragma unroll
        for (int p = 0; p < 3; ++p)
            if (p < 2 || lane < 16)
                ob[dyo + soff[p]] = my[ridx[p]];
    }
}

extern "C" void kernel_launch(void* const* d_in, const int* in_sizes, int n_in,
                              void* d_out, int out_size, void* d_ws, size_t ws_size,
                              hipStream_t stream)
{
    const float* x = (const float*)d_in[0];
    const float* y = (const float*)d_in[1];
    float* out = (float*)d_out;
    // kernel_size=9, stride=1 fixed by setup_inputs; hardcoded above.
    corr_k<<<1152, NT, 0, stream>>>(x, y, out);
}